// Round 9
// baseline (213.373 us; speedup 1.0000x reference)
//
#include <hip/hip_runtime.h>

#define NN    2048      // number of notes
#define SEGL  32768     // max note length
#define NH    8         // harmonics
#define DURS  4194304   // output duration samples
#define TILE  1024      // output samples per block (LDS accumulator)
#define BLK   256
#define NWAVE (BLK / 64)

// ws layout (element offsets into float*): [0,NN) fr ; [NN,2NN) st(int) ;
// [2NN,3NN) ln_clipped(int) ; [3NN,4NN) sin(64*fr) ; [4NN,5NN) cos(64*fr)

// accurate sincos (|x| < 2^18): Cody-Waite mod pi + deg-7/deg-8 Taylor,
// (-1)^k applied to both via xor.
__device__ __forceinline__ void sincos_acc(float x, float& s_out, float& c_out) {
    const float kq = rintf(x * 0.31830988618379067f);
    float r = fmaf(kq, -0x1.921FB6p+1f, x);     // pi_hi = fp32(pi), exact in fma
    r = fmaf(kq, 8.7422777e-8f, r);             // -(pi - pi_hi)
    const unsigned sgn = ((unsigned)(int)kq) << 31;
    const float y = r * r;
    float sp = fmaf(y, -1.9841270e-4f, 8.3333333e-3f);
    sp = fmaf(y, sp, -1.6666667e-1f);
    float s = fmaf(r * y, sp, r);
    float cp = fmaf(y, 2.4801587e-5f, -1.3888889e-3f);
    cp = fmaf(y, cp, 4.1666668e-2f);
    cp = fmaf(y, cp, -0.5f);
    float c = fmaf(y, cp, 1.0f);
    s_out = __uint_as_float(__float_as_uint(s) ^ sgn);
    c_out = __uint_as_float(__float_as_uint(c) ^ sgn);
}

__global__ __launch_bounds__(256) void note_init(
    const float* __restrict__ freq,
    const int*  __restrict__ starts,
    const int*  __restrict__ lens,
    float* __restrict__ ws)
{
    const int j = (int)blockIdx.x * 256 + (int)threadIdx.x;
    if (j >= NN) return;
    const float fr = freq[j];
    int st = starts[j];
    int ln = lens[j];
    int rem = DURS - st;             // out_len = min(start+len, dur) - start
    if (rem < 0) rem = 0;
    if (ln > rem) ln = rem;
    if (ln < 0) ln = 0;
    float sd, cd;
    sincos_acc(fr * 64.0f, sd, cd);  // 64*fr exact in fp32
    ws[j] = fr;
    ((int*)ws)[NN + j] = st;
    ((int*)ws)[2 * NN + j] = ln;
    ws[3 * NN + j] = sd;
    ws[4 * NN + j] = cd;
}

__global__ __launch_bounds__(BLK) void synth_gather(
    const int*  __restrict__ starts,
    const float* __restrict__ amps,
    const float* __restrict__ gainp,
    const float* __restrict__ ws,
    float* __restrict__ out)
{
    __shared__ float lacc[TILE];

    const int tile_lo = (int)blockIdx.x * TILE;
    const int tile_hi = tile_lo + TILE;

    // zero the tile accumulator
    for (int i = (int)threadIdx.x; i < TILE; i += BLK) lacc[i] = 0.0f;

    // Candidate notes = contiguous range [j0, j1) in the sorted start array.
    int lo = 0, hi = NN;
    const int v0 = tile_lo - SEGL;
    while (lo < hi) { int m = (lo + hi) >> 1; if (starts[m] > v0) hi = m; else lo = m + 1; }
    const int j0 = lo;
    lo = 0; hi = NN;
    while (lo < hi) { int m = (lo + hi) >> 1; if (starts[m] >= tile_hi) hi = m; else lo = m + 1; }
    const int j1 = lo;

    // Chebyshev-U basis combination of amps, pre-scaled by 2*g*log2(e),
    // rebased for Horner-in-cos: bt_k = b_k * 2^k.
    const float a0 = amps[0], a1 = amps[1], a2 = amps[2], a3 = amps[3];
    const float a4 = amps[4], a5 = amps[5], a6 = amps[6], a7 = amps[7];
    const float kg = gainp[0] * 2.8853900817779268f;   // 2*log2(e)
    const float bt7 = kg * a7 * 128.0f;
    const float bt6 = kg * a6 * 64.0f;
    const float bt5 = kg * (a5 - 6.0f * a7) * 32.0f;
    const float bt4 = kg * (a4 - 5.0f * a6) * 16.0f;
    const float bt3 = kg * (a3 - 4.0f * a5 + 10.0f * a7) * 8.0f;
    const float bt2 = kg * (a2 - 3.0f * a4 + 6.0f * a6) * 4.0f;
    const float bt1 = kg * (a1 - 2.0f * a3 + 3.0f * a5 - 4.0f * a7) * 2.0f;
    const float bt0 = kg * (a0 - a2 + a4 - a6);

    __syncthreads();

    const int wid  = (int)threadIdx.x >> 6;
    const int lane = (int)threadIdx.x & 63;

    // Each candidate is owned by exactly one wave; the wave walks the note's
    // full overlap with this tile in 64-sample chunks (lane = sample),
    // rotating (sin, cos) by 64*fr between chunks.
    for (int j = j0 + wid; j < j1; j += NWAVE) {
        const float fr = ws[j];
        const int st = ((const int*)ws)[NN + j];
        const int ln = ((const int*)ws)[2 * NN + j];
        const float sd = ws[3 * NN + j];
        const float cd = ws[4 * NN + j];

        int glo = st > tile_lo ? st : tile_lo;
        int ghi = st + ln; if (ghi > tile_hi) ghi = tile_hi;
        if (glo >= ghi) continue;

        int t = glo - st + lane;          // >= 0
        int o = glo - tile_lo + lane;
        const int tend = ghi - st;

        const float ph = fr * (float)t;   // fp32, matches reference arg here
        float s, c;
        sincos_acc(ph, s, c);

        const int nch = (ghi - glo + 63) >> 6;
        for (int ch = 0; ch < nch; ++ch) {
            // q = kg * Q(2*cos) via Horner in c with 2^k-scaled coefs
            float q = fmaf(c, bt7, bt6);
            q = fmaf(c, q, bt5);
            q = fmaf(c, q, bt4);
            q = fmaf(c, q, bt3);
            q = fmaf(c, q, bt2);
            q = fmaf(c, q, bt1);
            q = fmaf(c, q, bt0);
            const float e = __builtin_amdgcn_exp2f(s * q);
            const float rc = __builtin_amdgcn_rcpf(e + 1.0f);
            const float term = fmaf(-2.0f, rc, 1.0f);
            if (t < tend) atomicAdd(&lacc[o], term);   // ds_add_f32, conflict-free
            // rotate phase by 64*fr
            const float sn = fmaf(c, sd, s * cd);
            c = fmaf(-s, sd, c * cd);
            s = sn;
            t += 64;
            o += 64;
        }
    }

    __syncthreads();

    // coalesced writeout: one float4 per thread
    {
        const int i = (int)threadIdx.x * 4;
        float4 v = *reinterpret_cast<const float4*>(&lacc[i]);
        *reinterpret_cast<float4*>(&out[tile_lo + i]) = v;
    }
}

extern "C" void kernel_launch(void* const* d_in, const int* in_sizes, int n_in,
                              void* d_out, int out_size, void* d_ws, size_t ws_size,
                              hipStream_t stream) {
    const float* freq   = (const float*)d_in[0];
    const float* amps   = (const float*)d_in[1];
    const float* gain   = (const float*)d_in[2];
    const int*   starts = (const int*)d_in[3];
    const int*   lens   = (const int*)d_in[4];
    float* out = (float*)d_out;
    float* ws  = (float*)d_ws;   // 5*NN floats = 40 KB

    note_init<<<(NN + 255) / 256, 256, 0, stream>>>(freq, starts, lens, ws);
    synth_gather<<<DURS / TILE, BLK, 0, stream>>>(starts, amps, gain, ws, out);
}

// Round 10
// 36.805 us; speedup vs baseline: 5.7974x; 5.7974x over previous
//
#include <hip/hip_runtime.h>

#define NN    2048      // number of notes
#define SEGL  32768     // max note length
#define NH    8         // harmonics
#define DURS  4194304   // output duration samples
#define BLK   128
#define S     8                 // consecutive samples per thread
#define TILE  (BLK * S)         // 1024
#define MAXC  64                // staged candidates per chunk (expected ~16)

// accurate sincos (|x| < 2^18): Cody-Waite mod pi + deg-7/deg-8 Taylor,
// (-1)^k applied to both via xor. For |x| < pi/2 it reduces to the raw polys.
__device__ __forceinline__ void sincos_acc(float x, float& s_out, float& c_out) {
    const float kq = rintf(x * 0.31830988618379067f);
    float r = fmaf(kq, -0x1.921FB6p+1f, x);     // pi_hi = fp32(pi), exact in fma
    r = fmaf(kq, 8.7422777e-8f, r);             // -(pi - pi_hi)
    const unsigned sgn = ((unsigned)(int)kq) << 31;
    const float y = r * r;
    float sp = fmaf(y, -1.9841270e-4f, 8.3333333e-3f);
    sp = fmaf(y, sp, -1.6666667e-1f);
    float s = fmaf(r * y, sp, r);
    float cp = fmaf(y, 2.4801587e-5f, -1.3888889e-3f);
    cp = fmaf(y, cp, 4.1666668e-2f);
    cp = fmaf(y, cp, -0.5f);
    float c = fmaf(y, cp, 1.0f);
    s_out = __uint_as_float(__float_as_uint(s) ^ sgn);
    c_out = __uint_as_float(__float_as_uint(c) ^ sgn);
}

__global__ __launch_bounds__(BLK) void synth_gather(
    const float* __restrict__ freq,
    const float* __restrict__ amps,
    const float* __restrict__ gainp,
    const int*  __restrict__ starts,
    const int*  __restrict__ lens,
    float* __restrict__ out)
{
    __shared__ float4 s_c0[MAXC];   // {freq, start(bits), len(bits), -}
    __shared__ float2 s_c1[MAXC];   // {sin(freq), cos(freq)} per-candidate

    const int tile_lo = (int)blockIdx.x * TILE;
    const int tile_hi = tile_lo + TILE;

    // Candidate notes = contiguous range [j0, j1) in the sorted start array.
    int lo = 0, hi = NN;
    const int v0 = tile_lo - SEGL;
    while (lo < hi) { int m = (lo + hi) >> 1; if (starts[m] > v0) hi = m; else lo = m + 1; }
    const int j0 = lo;
    lo = 0; hi = NN;
    while (lo < hi) { int m = (lo + hi) >> 1; if (starts[m] >= tile_hi) hi = m; else lo = m + 1; }
    const int j1 = lo;

    // Chebyshev-U basis combination of amps, pre-scaled by 2*g*log2(e),
    // rebased for Horner-in-cos: bt_k = b_k * 2^k.
    const float a0 = amps[0], a1 = amps[1], a2 = amps[2], a3 = amps[3];
    const float a4 = amps[4], a5 = amps[5], a6 = amps[6], a7 = amps[7];
    const float kg = gainp[0] * 2.8853900817779268f;   // 2*log2(e)
    const float bt7 = kg * a7 * 128.0f;
    const float bt6 = kg * a6 * 64.0f;
    const float bt5 = kg * (a5 - 6.0f * a7) * 32.0f;
    const float bt4 = kg * (a4 - 5.0f * a6) * 16.0f;
    const float bt3 = kg * (a3 - 4.0f * a5 + 10.0f * a7) * 8.0f;
    const float bt2 = kg * (a2 - 3.0f * a4 + 6.0f * a6) * 4.0f;
    const float bt1 = kg * (a1 - 2.0f * a3 + 3.0f * a5 - 4.0f * a7) * 2.0f;
    const float bt0 = kg * (a0 - a2 + a4 - a6);

    float acc[S];
#pragma unroll
    for (int i = 0; i < S; ++i) acc[i] = 0.0f;

    const int base = tile_lo + (int)threadIdx.x * S;

    for (int jb = j0; jb < j1; jb += MAXC) {
        const int cchunk = min(j1 - jb, MAXC);
        __syncthreads();
        for (int c = (int)threadIdx.x; c < cchunk; c += BLK) {
            int j = jb + c;
            const float fr = freq[j];
            int st = starts[j];
            int ln = lens[j];
            int rem = DURS - st;          // out_len = min(start+len, dur) - start
            if (rem < 0) rem = 0;
            if (ln > rem) ln = rem;
            if (ln < 0) ln = 0;
            float4 v;
            v.x = fr;
            v.y = __int_as_float(st);
            v.z = __int_as_float(ln);
            v.w = 0.0f;
            s_c0[c] = v;
            float sd, cd;                 // per-candidate rotation constants
            sincos_acc(fr, sd, cd);       // fr in [0,1): kq==0 path, exact polys
            s_c1[c] = make_float2(sd, cd);
        }
        __syncthreads();

        for (int c = 0; c < cchunk; ++c) {
            const float4 v = s_c0[c];
            const float fr = v.x;
            const int st = __float_as_int(v.y);
            const int ln = __float_as_int(v.z);
            const int t0 = base - st;
            // this thread's run [t0, t0+S) vs valid [0, ln)
            if (t0 >= ln || t0 + (S - 1) < 0) continue;
            const float2 w = s_c1[c];
            const float sd = w.x;
            const float cd = w.y;

            // anchor phase at this thread's first sample (reference-rounded arg)
            const float ph0 = fr * (float)t0;
            float s, cc;
            sincos_acc(ph0, s, cc);

            if (t0 >= 0 && t0 + S <= ln) {
                // full-cover fast path: no per-sample validity checks
#pragma unroll
                for (int i = 0; i < S; ++i) {
                    float q = fmaf(cc, bt7, bt6);
                    q = fmaf(cc, q, bt5);
                    q = fmaf(cc, q, bt4);
                    q = fmaf(cc, q, bt3);
                    q = fmaf(cc, q, bt2);
                    q = fmaf(cc, q, bt1);
                    q = fmaf(cc, q, bt0);
                    const float e = __builtin_amdgcn_exp2f(s * q);
                    const float rc = __builtin_amdgcn_rcpf(e + 1.0f);
                    acc[i] += fmaf(-2.0f, rc, 1.0f);
                    if (i < S - 1) {                         // last step DCE'd
                        const float sn = fmaf(cc, sd, s * cd);
                        cc = fmaf(-s, sd, cc * cd);
                        s = sn;
                    }
                }
            } else {
                // boundary path: per-sample mask
#pragma unroll
                for (int i = 0; i < S; ++i) {
                    float q = fmaf(cc, bt7, bt6);
                    q = fmaf(cc, q, bt5);
                    q = fmaf(cc, q, bt4);
                    q = fmaf(cc, q, bt3);
                    q = fmaf(cc, q, bt2);
                    q = fmaf(cc, q, bt1);
                    q = fmaf(cc, q, bt0);
                    const float e = __builtin_amdgcn_exp2f(s * q);
                    const float rc = __builtin_amdgcn_rcpf(e + 1.0f);
                    const float term = fmaf(-2.0f, rc, 1.0f);
                    const bool valid = (unsigned)(t0 + i) < (unsigned)ln;
                    acc[i] += valid ? term : 0.0f;
                    if (i < S - 1) {
                        const float sn = fmaf(cc, sd, s * cd);
                        cc = fmaf(-s, sd, cc * cd);
                        s = sn;
                    }
                }
            }
        }
    }

#pragma unroll
    for (int i = 0; i < S; i += 4) {
        float4 o;
        o.x = acc[i]; o.y = acc[i + 1]; o.z = acc[i + 2]; o.w = acc[i + 3];
        *reinterpret_cast<float4*>(&out[base + i]) = o;
    }
}

extern "C" void kernel_launch(void* const* d_in, const int* in_sizes, int n_in,
                              void* d_out, int out_size, void* d_ws, size_t ws_size,
                              hipStream_t stream) {
    const float* freq   = (const float*)d_in[0];
    const float* amps   = (const float*)d_in[1];
    const float* gain   = (const float*)d_in[2];
    const int*   starts = (const int*)d_in[3];
    const int*   lens   = (const int*)d_in[4];
    float* out = (float*)d_out;

    const int grid = DURS / TILE;   // 4096 blocks
    synth_gather<<<grid, BLK, 0, stream>>>(freq, amps, gain, starts, lens, out);
}